// Round 5
// baseline (212.243 us; speedup 1.0000x reference)
//
#include <hip/hip_runtime.h>
#include <stdint.h>

typedef __bf16 bf16_t;
typedef __bf16 bf16x8 __attribute__((ext_vector_type(8)));
typedef float f32x4 __attribute__((ext_vector_type(4)));
typedef float f32x16 __attribute__((ext_vector_type(16)));
typedef unsigned int u32x2 __attribute__((ext_vector_type(2)));

#define DEV __device__ __forceinline__

DEV void gload_lds16(const void* g, void* lds) {
  __builtin_amdgcn_global_load_lds(
      (const __attribute__((address_space(1))) uint32_t*)g,
      (__attribute__((address_space(3))) uint32_t*)lds, 16, 0, 0);
}

DEV float fexp2(float x) {
#if __has_builtin(__builtin_amdgcn_exp2f)
  return __builtin_amdgcn_exp2f(x);
#else
  return exp2f(x);
#endif
}

DEV uint32_t pk_bf16(float a, float b) {
  uint32_t lo = (uint32_t)__builtin_bit_cast(uint16_t, (bf16_t)a);
  uint32_t hi = (uint32_t)__builtin_bit_cast(uint16_t, (bf16_t)b);
  return lo | (hi << 16);
}

// ---------------------------------------------------------------- K0: hs -> bf16
__global__ __launch_bounds__(256) void cvt_hs(const float* __restrict__ x,
                                              bf16_t* __restrict__ y) {
  int i = blockIdx.x * 256 + threadIdx.x;
  float4 v = ((const float4*)x)[i];
  ((uint2*)y)[i] = make_uint2(pk_bf16(v.x, v.y), pk_bf16(v.z, v.w));
}

// ------------------------------------------- K1: W[k][n] (x3) -> WT[n][k] bf16
__global__ __launch_bounds__(256) void cvt_w(const float* __restrict__ Wq,
                                             const float* __restrict__ Wk,
                                             const float* __restrict__ Wv,
                                             bf16_t* __restrict__ WT) {
  __shared__ float T[32][36];
  const int bx = blockIdx.x;   // n tile 0..71 (over 2304)
  const int by = blockIdx.y;   // k tile 0..23 (over 768)
  const int p = bx / 24;
  const float* W = (p == 0) ? Wq : ((p == 1) ? Wk : Wv);
  const int n0 = bx * 32, nn0 = n0 - p * 768, k0 = by * 32;
  const int t = threadIdx.x;
  {
    int r = t >> 3, c4 = (t & 7) * 4;
    float4 v = *(const float4*)&W[(size_t)(k0 + r) * 768 + nn0 + c4];
    T[r][c4 + 0] = v.x; T[r][c4 + 1] = v.y; T[r][c4 + 2] = v.z; T[r][c4 + 3] = v.w;
  }
  __syncthreads();
  {
    int nr = t >> 3, kc = (t & 7) * 4;
    uint32_t lo = pk_bf16(T[kc + 0][nr], T[kc + 1][nr]);
    uint32_t hi = pk_bf16(T[kc + 2][nr], T[kc + 3][nr]);
    *(uint2*)&WT[(size_t)(n0 + nr) * 768 + k0 + kc] = make_uint2(lo, hi);
  }
}

// ------------------------------------------------- K2: C[4096,2304] = A @ W (+b)
// K-projection output is pre-scaled by log2(e)/8 (softmax scale folded in).
// v2: double-buffered LDS pipeline (round-3 win).
__global__ __launch_bounds__(256) void gemm_qkv(
    const bf16_t* __restrict__ A, const bf16_t* __restrict__ Wt,
    const float* __restrict__ bq, const float* __restrict__ bk,
    const float* __restrict__ bv, bf16_t* __restrict__ Qo,
    bf16_t* __restrict__ Ko, bf16_t* __restrict__ VTo) {
  __shared__ __align__(16) char smem[65536];  // 2 x (As 16K + Bs 16K); Cs union
  bf16_t* Cs = (bf16_t*)smem;  // 128x136 epilogue scratch
  const int bx = blockIdx.x;  // 0..17 (n)
  const int by = blockIdx.y;  // 0..31 (m)
  const int m0 = by * 128, n0 = bx * 128;
  const int tid = threadIdx.x, w = tid >> 6, lane = tid & 63;
  const int mw = (w & 1) * 64, nw = (w >> 1) * 64;
  const int quad = lane >> 4, col = lane & 15;

  f32x4 acc[4][4];
  for (int i = 0; i < 4; i++)
    for (int j = 0; j < 4; j++) acc[i][j] = (f32x4){0.f, 0.f, 0.f, 0.f};

  const int srow = w * 32 + (lane >> 3);
  const int scol = (lane & 7) * 8;
  const bf16_t* ag = A + (size_t)(m0 + srow) * 768 + scol;
  const bf16_t* bg = Wt + (size_t)(n0 + srow) * 768 + scol;

  auto stageg = [&](int kk, int bf) {
    const int k0 = kk * 64;
    bf16_t* dA = (bf16_t*)(smem + bf * 32768) + (w * 32) * 64;
    bf16_t* dB = (bf16_t*)(smem + bf * 32768 + 16384) + (w * 32) * 64;
#pragma unroll
    for (int i = 0; i < 4; i++) {
      gload_lds16(ag + (size_t)i * 8 * 768 + k0, dA + i * 8 * 64);
      gload_lds16(bg + (size_t)i * 8 * 768 + k0, dB + i * 8 * 64);
    }
  };

  stageg(0, 0);
  __syncthreads();  // one exposed drain at prologue only

  for (int kk = 0; kk < 12; ++kk) {
    const int bf = kk & 1;
    if (kk < 11) stageg(kk + 1, bf ^ 1);
    __builtin_amdgcn_sched_barrier(0);  // pin load issue ahead of compute
    const bf16_t* As = (const bf16_t*)(smem + bf * 32768);
    const bf16_t* Bs = (const bf16_t*)(smem + bf * 32768 + 16384);
#pragma unroll
    for (int ks = 0; ks < 2; ++ks) {
      bf16x8 af[4], bfr[4];
#pragma unroll
      for (int mt = 0; mt < 4; ++mt)
        af[mt] = *(const bf16x8*)&As[(mw + mt * 16 + col) * 64 + ks * 32 + quad * 8];
#pragma unroll
      for (int nt = 0; nt < 4; ++nt)
        bfr[nt] = *(const bf16x8*)&Bs[(nw + nt * 16 + col) * 64 + ks * 32 + quad * 8];
#pragma unroll
      for (int mt = 0; mt < 4; ++mt)
#pragma unroll
        for (int nt = 0; nt < 4; ++nt)
          acc[mt][nt] = __builtin_amdgcn_mfma_f32_16x16x32_bf16(
              af[mt], bfr[nt], acc[mt][nt], 0, 0, 0);
    }
    __syncthreads();  // publishes stage(kk+1); all reads of buf done
  }

  const int p = bx / 6;
  const float* bp = (p == 0) ? bq : ((p == 1) ? bk : bv);
  const float kscale = (p == 1) ? 0.18033688011112042f : 1.0f;  // log2(e)/sqrt(64)
  const int bb0 = m0 >> 11, s0 = m0 & 2047;
  if (p < 2) {
#pragma unroll
    for (int nt = 0; nt < 4; nt++) {
      int n = nw + nt * 16 + col;
      float bias = bp[n0 + n - p * 768];
#pragma unroll
      for (int mt = 0; mt < 4; mt++)
#pragma unroll
        for (int r = 0; r < 4; r++) {
          int m = mw + mt * 16 + quad * 4 + r;
          Cs[m * 136 + n] = (bf16_t)((acc[mt][nt][r] + bias) * kscale);
        }
    }
    __syncthreads();
    bf16_t* dst = (p == 0) ? Qo : Ko;
#pragma unroll
    for (int i = 0; i < 8; i++) {
      int idx = i * 256 + tid;
      int m = idx >> 4, c = idx & 15;
      bf16x8 v = *(const bf16x8*)&Cs[m * 136 + c * 8];
      int nn = n0 - p * 768 + c * 8;
      int hq = nn >> 6, hd = nn & 63;
      *(bf16x8*)&dst[(size_t)((bb0 * 12 + hq) * 2048 + s0 + m) * 64 + hd] = v;
    }
  } else {
#pragma unroll
    for (int nt = 0; nt < 4; nt++) {
      int n = nw + nt * 16 + col;
      float bias = bp[n0 + n - 1536];
#pragma unroll
      for (int mt = 0; mt < 4; mt++)
#pragma unroll
        for (int r = 0; r < 4; r++) {
          int m = mw + mt * 16 + quad * 4 + r;
          Cs[n * 136 + m] = (bf16_t)(acc[mt][nt][r] + bias);
        }
    }
    __syncthreads();
#pragma unroll
    for (int i = 0; i < 8; i++) {
      int idx = i * 256 + tid;
      int n = idx >> 4, c = idx & 15;
      bf16x8 v = *(const bf16x8*)&Cs[n * 136 + c * 8];
      int nn = n0 - 1536 + n;
      int hq = nn >> 6, hd = nn & 63;
      *(bf16x8*)&VTo[((size_t)(bb0 * 12 + hq) * 64 + hd) * 2048 + s0 + c * 8] = v;
    }
  }
}

// ---------------------------------------------------------------- K3: attention
// v9: barrier-free register-direct streaming. Round-4 evidence: ksplit=4
// occupancy push regressed 2x on partial+fetch traffic (35->194 MB) -- occupancy
// bought with HBM traffic loses. Round-3 evidence: at ksplit=2 the kernel is
// latency-bound with per-iter wall ~5.7k cy vs ~700 cy chain; the exposed part
// is the 4-wave barrier lockstep + LDS round-trip. v9 removes both: K/V are
// L2-resident (1.5MB/XCD), so each wave streams K and V fragments directly
// global->VGPR (same per-lane pattern as the Q load -- no transpose needed),
// double-buffered in registers, prefetch issued after each compute block.
// Zero __syncthreads, zero LDS in the main loop, KVBLK=32, 32 iters/wave.
__global__ __launch_bounds__(256, 3) void attn(const bf16_t* __restrict__ Q,
                                               const bf16_t* __restrict__ K,
                                               const bf16_t* __restrict__ VT,
                                               float* __restrict__ Op,
                                               float* __restrict__ lp) {
  __shared__ float Of[4][2048];  // 32KB epilogue scratch, per-wave private
  const int id = blockIdx.x;     // 0..767
  const int rr0 = id >> 3;       // 0..95
  const int bh = (id & 7) * 3 + (rr0 >> 5);  // XCD id&7 owns 3 consecutive bh
  const int w5 = rr0 & 31;
  const int qt = w5 & 15, sp = w5 >> 4;      // q-tile 0..15, key-split 0..1
  const int tid = threadIdx.x, wv = tid >> 6, lane = tid & 63;
  const int lq = lane & 31, half = lane >> 5;
  const int q0 = qt * 128 + wv * 32;

  bf16x8 qf0, qf1, qf2, qf3;  // B-frags of Q^T (per-lane query = lq)
  {
    const bf16_t* qp = Q + (size_t)(bh * 2048 + q0 + lq) * 64 + half * 8;
    qf0 = *(const bf16x8*)(qp + 0);
    qf1 = *(const bf16x8*)(qp + 16);
    qf2 = *(const bf16x8*)(qp + 32);
    qf3 = *(const bf16x8*)(qp + 48);
  }

  f32x16 oacc[2];  // O^T partial: col=q (lane), rows=d
  for (int i = 0; i < 16; i++) { oacc[0][i] = 0.f; oacc[1][i] = 0.f; }
  float l0 = 0.f, l1 = 0.f, l2 = 0.f, l3 = 0.f;

  // per-lane stream bases (bf16 elements)
  //  kf[ks] @ kb: kp + kb*2048 + ks*16  -> K[kb*32+lq][ks*16+half*8 ..+8]
  //  vf[dt][c] @ kb: vp + dt*65536 + kb*32 + c*16 -> VT[dt*32+lq][kb*32+(2c+half)*8]
  const bf16_t* kp = K + ((size_t)bh * 2048 + sp * 1024 + lq) * 64 + half * 8;
  const bf16_t* vp = VT + (size_t)bh * 131072 + (size_t)lq * 2048 + sp * 1024 + half * 8;

#define LOADKV(S, kbv)                                                \
  S##k0 = *(const bf16x8*)(kp + (size_t)(kbv) * 2048 + 0);            \
  S##k1 = *(const bf16x8*)(kp + (size_t)(kbv) * 2048 + 16);           \
  S##k2 = *(const bf16x8*)(kp + (size_t)(kbv) * 2048 + 32);           \
  S##k3 = *(const bf16x8*)(kp + (size_t)(kbv) * 2048 + 48);           \
  S##v00 = *(const bf16x8*)(vp + (kbv) * 32 + 0);                     \
  S##v01 = *(const bf16x8*)(vp + (kbv) * 32 + 16);                    \
  S##v10 = *(const bf16x8*)(vp + 65536 + (kbv) * 32 + 0);             \
  S##v11 = *(const bf16x8*)(vp + 65536 + (kbv) * 32 + 16);

#if __has_builtin(__builtin_amdgcn_permlane32_swap)
#define XHALF(a, b, F, wd)                                   \
  { u32x2 sw_ = __builtin_amdgcn_permlane32_swap(a, b, false, false); \
    F.u[wd] = sw_.x; F.u[2 + wd] = sw_.y; }
#else
#define XHALF(a, b, F, wd)                                   \
  { uint32_t s_ = half ? (a) : (b);                          \
    uint32_t rx_ = __shfl_xor(s_, 32);                       \
    uint32_t ow_ = half ? (b) : (a);                         \
    F.u[wd] = half ? rx_ : ow_; F.u[2 + wd] = half ? ow_ : rx_; }
#endif

#define COMPUTE(S)                                                          \
  {                                                                         \
    f32x16 sacc;                                                            \
    for (int i_ = 0; i_ < 16; i_++) sacc[i_] = 0.f;                         \
    __builtin_amdgcn_s_setprio(1);                                          \
    sacc = __builtin_amdgcn_mfma_f32_32x32x16_bf16(S##k0, qf0, sacc, 0, 0, 0); \
    sacc = __builtin_amdgcn_mfma_f32_32x32x16_bf16(S##k1, qf1, sacc, 0, 0, 0); \
    sacc = __builtin_amdgcn_mfma_f32_32x32x16_bf16(S##k2, qf2, sacc, 0, 0, 0); \
    sacc = __builtin_amdgcn_mfma_f32_32x32x16_bf16(S##k3, qf3, sacc, 0, 0, 0); \
    __builtin_amdgcn_s_setprio(0);                                          \
    _Pragma("unroll")                                                       \
    for (int rr_ = 0; rr_ < 16; rr_++) sacc[rr_] = fexp2(sacc[rr_]);        \
    _Pragma("unroll")                                                       \
    for (int rr_ = 0; rr_ < 16; rr_ += 4) {                                 \
      l0 += sacc[rr_ + 0]; l1 += sacc[rr_ + 1];                             \
      l2 += sacc[rr_ + 2]; l3 += sacc[rr_ + 3];                             \
    }                                                                       \
    uint32_t q00 = pk_bf16(sacc[0], sacc[1]), q01 = pk_bf16(sacc[2], sacc[3]);   \
    uint32_t q10 = pk_bf16(sacc[4], sacc[5]), q11 = pk_bf16(sacc[6], sacc[7]);   \
    uint32_t q20 = pk_bf16(sacc[8], sacc[9]), q21 = pk_bf16(sacc[10], sacc[11]); \
    uint32_t q30 = pk_bf16(sacc[12], sacc[13]), q31 = pk_bf16(sacc[14], sacc[15]); \
    union { uint32_t u[4]; bf16x8 v; } F0, F1;                              \
    XHALF(q00, q10, F0, 0); XHALF(q01, q11, F0, 1);                         \
    XHALF(q20, q30, F1, 0); XHALF(q21, q31, F1, 1);                         \
    __builtin_amdgcn_s_setprio(1);                                          \
    oacc[0] = __builtin_amdgcn_mfma_f32_32x32x16_bf16(S##v00, F0.v, oacc[0], 0, 0, 0); \
    oacc[1] = __builtin_amdgcn_mfma_f32_32x32x16_bf16(S##v10, F0.v, oacc[1], 0, 0, 0); \
    oacc[0] = __builtin_amdgcn_mfma_f32_32x32x16_bf16(S##v01, F1.v, oacc[0], 0, 0, 0); \
    oacc[1] = __builtin_amdgcn_mfma_f32_32x32x16_bf16(S##v11, F1.v, oacc[1], 0, 0, 0); \
    __builtin_amdgcn_s_setprio(0);                                          \
  }

  bf16x8 Ak0, Ak1, Ak2, Ak3, Av00, Av01, Av10, Av11;
  bf16x8 Bk0, Bk1, Bk2, Bk3, Bv00, Bv01, Bv10, Bv11;

  LOADKV(A, 0);
  LOADKV(B, 1);

  for (int kb = 0; kb < 32; kb += 2) {
    COMPUTE(A);
    if (kb + 2 < 32) { LOADKV(A, kb + 2); }
    __builtin_amdgcn_sched_barrier(0);  // pin A-prefetch issue here
    COMPUTE(B);
    if (kb + 3 < 32) { LOADKV(B, kb + 3); }
    __builtin_amdgcn_sched_barrier(0);  // pin B-prefetch issue here
  }

#undef LOADKV
#undef XHALF
#undef COMPUTE

  // epilogue: partial l + unnormalized partial O^T -> Op[q][d] rows.
  // Each wave owns its private 8KB of Of -- no cross-wave sync needed.
  float l_own = (l0 + l1) + (l2 + l3);
  float l_tot = l_own + __shfl_xor(l_own, 32);
  if (half == 0) lp[((size_t)sp * 24 + bh) * 2048 + q0 + lq] = l_tot;
  float* Ow = &Of[wv][0];
#pragma unroll
  for (int dt = 0; dt < 2; dt++)
#pragma unroll
    for (int rr = 0; rr < 16; rr++) {
      int d = dt * 32 + (rr & 3) + 8 * (rr >> 2) + 4 * half;
      int g = d >> 2, wd = d & 3;
      Ow[lq * 64 + ((g ^ (lq & 15)) * 4) + wd] = oacc[dt][rr];
    }
  float* ob = Op + (((size_t)sp * 24 + bh) * 2048 + q0) * 64;
#pragma unroll
  for (int i = 0; i < 8; i++) {
    int idx = i * 64 + lane;
    int qq = idx >> 4, c = idx & 15;
    f32x4 v = *(f32x4*)&Ow[qq * 64 + ((c ^ (qq & 15)) * 4)];
    *(f32x4*)&ob[(size_t)qq * 64 + c * 4] = v;
  }
}

// ------------------------------------------------- K4: combine split-K partials
// out[b][q][h*64+d] = (Op0 + Op1) / (l0 + l1), with head-merge transpose.
__global__ __launch_bounds__(256) void combine(const float* __restrict__ Op,
                                               const float* __restrict__ lp,
                                               float* __restrict__ out) {
  int g = blockIdx.x * 256 + threadIdx.x;  // over 24*2048*16 = 786432
  int bh = g >> 15;
  int rem = g & 32767;
  int q = rem >> 4, c = rem & 15;
  const size_t plane = (size_t)24 * 2048 * 64;
  size_t o0 = ((size_t)bh * 2048 + q) * 64 + c * 4;
  f32x4 a = *(const f32x4*)&Op[o0];
  f32x4 b2 = *(const f32x4*)&Op[plane + o0];
  float l = lp[bh * 2048 + q] + lp[24 * 2048 + bh * 2048 + q];
  float inv = 1.0f / l;
  int b = bh / 12, head = bh % 12;
  f32x4 r;
#pragma unroll
  for (int j = 0; j < 4; j++) r[j] = (a[j] + b2[j]) * inv;
  *(f32x4*)&out[((size_t)b * 2048 + q) * 768 + head * 64 + c * 4] = r;
}

// -------------------------------------------------------------------- launcher
extern "C" void kernel_launch(void* const* d_in, const int* in_sizes, int n_in,
                              void* d_out, int out_size, void* d_ws, size_t ws_size,
                              hipStream_t stream) {
  const float* hs = (const float*)d_in[0];
  const float* Wq = (const float*)d_in[1];
  const float* bq = (const float*)d_in[2];
  const float* Wk = (const float*)d_in[3];
  const float* bk = (const float*)d_in[4];
  const float* Wv = (const float*)d_in[5];
  const float* bv = (const float*)d_in[6];
  float* out = (float*)d_out;

  char* w = (char*)d_ws;
  bf16_t* hsb = (bf16_t*)w; w += (size_t)4096 * 768 * 2;
  bf16_t* wtb = (bf16_t*)w; w += (size_t)2304 * 768 * 2;
  bf16_t* Qb  = (bf16_t*)w; w += (size_t)24 * 2048 * 64 * 2;
  bf16_t* Kb  = (bf16_t*)w; w += (size_t)24 * 2048 * 64 * 2;
  bf16_t* VTb = (bf16_t*)w; w += (size_t)24 * 2048 * 64 * 2;
  float* Opw  = (float*)w;  w += (size_t)2 * 24 * 2048 * 64 * 4;  // 25.2 MB
  float* lpw  = (float*)w;                                        // 0.39 MB

  hipLaunchKernelGGL(cvt_hs, dim3(3072), dim3(256), 0, stream, hs, hsb);
  hipLaunchKernelGGL(cvt_w, dim3(72, 24), dim3(256), 0, stream, Wq, Wk, Wv, wtb);
  hipLaunchKernelGGL(gemm_qkv, dim3(18, 32), dim3(256), 0, stream, hsb, wtb, bq,
                     bk, bv, Qb, Kb, VTb);
  hipLaunchKernelGGL(attn, dim3(768), dim3(256), 0, stream, Qb, Kb, VTb, Opw, lpw);
  hipLaunchKernelGGL(combine, dim3(3072), dim3(256), 0, stream, Opw, lpw, out);
}

// Round 6
// 182.330 us; speedup vs baseline: 1.1641x; 1.1641x over previous
//
#include <hip/hip_runtime.h>
#include <stdint.h>

typedef __bf16 bf16_t;
typedef __bf16 bf16x8 __attribute__((ext_vector_type(8)));
typedef float f32x4 __attribute__((ext_vector_type(4)));
typedef float f32x16 __attribute__((ext_vector_type(16)));
typedef unsigned int u32x2 __attribute__((ext_vector_type(2)));

#define DEV __device__ __forceinline__

DEV void gload_lds16(const void* g, void* lds) {
  __builtin_amdgcn_global_load_lds(
      (const __attribute__((address_space(1))) uint32_t*)g,
      (__attribute__((address_space(3))) uint32_t*)lds, 16, 0, 0);
}

DEV float fexp2(float x) {
#if __has_builtin(__builtin_amdgcn_exp2f)
  return __builtin_amdgcn_exp2f(x);
#else
  return exp2f(x);
#endif
}

DEV uint32_t pk_bf16(float a, float b) {
  uint32_t lo = (uint32_t)__builtin_bit_cast(uint16_t, (bf16_t)a);
  uint32_t hi = (uint32_t)__builtin_bit_cast(uint16_t, (bf16_t)b);
  return lo | (hi << 16);
}

// ---------------------------------------------------------------- K0: hs -> bf16
__global__ __launch_bounds__(256) void cvt_hs(const float* __restrict__ x,
                                              bf16_t* __restrict__ y) {
  int i = blockIdx.x * 256 + threadIdx.x;
  float4 v = ((const float4*)x)[i];
  ((uint2*)y)[i] = make_uint2(pk_bf16(v.x, v.y), pk_bf16(v.z, v.w));
}

// ------------------------------------------- K1: W[k][n] (x3) -> WT[n][k] bf16
__global__ __launch_bounds__(256) void cvt_w(const float* __restrict__ Wq,
                                             const float* __restrict__ Wk,
                                             const float* __restrict__ Wv,
                                             bf16_t* __restrict__ WT) {
  __shared__ float T[32][36];
  const int bx = blockIdx.x;   // n tile 0..71 (over 2304)
  const int by = blockIdx.y;   // k tile 0..23 (over 768)
  const int p = bx / 24;
  const float* W = (p == 0) ? Wq : ((p == 1) ? Wk : Wv);
  const int n0 = bx * 32, nn0 = n0 - p * 768, k0 = by * 32;
  const int t = threadIdx.x;
  {
    int r = t >> 3, c4 = (t & 7) * 4;
    float4 v = *(const float4*)&W[(size_t)(k0 + r) * 768 + nn0 + c4];
    T[r][c4 + 0] = v.x; T[r][c4 + 1] = v.y; T[r][c4 + 2] = v.z; T[r][c4 + 3] = v.w;
  }
  __syncthreads();
  {
    int nr = t >> 3, kc = (t & 7) * 4;
    uint32_t lo = pk_bf16(T[kc + 0][nr], T[kc + 1][nr]);
    uint32_t hi = pk_bf16(T[kc + 2][nr], T[kc + 3][nr]);
    *(uint2*)&WT[(size_t)(n0 + nr) * 768 + k0 + kc] = make_uint2(lo, hi);
  }
}

// ------------------------------------------------- K2: C[4096,2304] = A @ W (+b)
// K-projection output is pre-scaled by log2(e)/8 (softmax scale folded in).
// v2: double-buffered LDS pipeline (round-3 win).
__global__ __launch_bounds__(256) void gemm_qkv(
    const bf16_t* __restrict__ A, const bf16_t* __restrict__ Wt,
    const float* __restrict__ bq, const float* __restrict__ bk,
    const float* __restrict__ bv, bf16_t* __restrict__ Qo,
    bf16_t* __restrict__ Ko, bf16_t* __restrict__ VTo) {
  __shared__ __align__(16) char smem[65536];  // 2 x (As 16K + Bs 16K); Cs union
  bf16_t* Cs = (bf16_t*)smem;  // 128x136 epilogue scratch
  const int bx = blockIdx.x;  // 0..17 (n)
  const int by = blockIdx.y;  // 0..31 (m)
  const int m0 = by * 128, n0 = bx * 128;
  const int tid = threadIdx.x, w = tid >> 6, lane = tid & 63;
  const int mw = (w & 1) * 64, nw = (w >> 1) * 64;
  const int quad = lane >> 4, col = lane & 15;

  f32x4 acc[4][4];
  for (int i = 0; i < 4; i++)
    for (int j = 0; j < 4; j++) acc[i][j] = (f32x4){0.f, 0.f, 0.f, 0.f};

  const int srow = w * 32 + (lane >> 3);
  const int scol = (lane & 7) * 8;
  const bf16_t* ag = A + (size_t)(m0 + srow) * 768 + scol;
  const bf16_t* bg = Wt + (size_t)(n0 + srow) * 768 + scol;

  auto stageg = [&](int kk, int bf) {
    const int k0 = kk * 64;
    bf16_t* dA = (bf16_t*)(smem + bf * 32768) + (w * 32) * 64;
    bf16_t* dB = (bf16_t*)(smem + bf * 32768 + 16384) + (w * 32) * 64;
#pragma unroll
    for (int i = 0; i < 4; i++) {
      gload_lds16(ag + (size_t)i * 8 * 768 + k0, dA + i * 8 * 64);
      gload_lds16(bg + (size_t)i * 8 * 768 + k0, dB + i * 8 * 64);
    }
  };

  stageg(0, 0);
  __syncthreads();  // one exposed drain at prologue only

  for (int kk = 0; kk < 12; ++kk) {
    const int bf = kk & 1;
    if (kk < 11) stageg(kk + 1, bf ^ 1);
    __builtin_amdgcn_sched_barrier(0);  // pin load issue ahead of compute
    const bf16_t* As = (const bf16_t*)(smem + bf * 32768);
    const bf16_t* Bs = (const bf16_t*)(smem + bf * 32768 + 16384);
#pragma unroll
    for (int ks = 0; ks < 2; ++ks) {
      bf16x8 af[4], bfr[4];
#pragma unroll
      for (int mt = 0; mt < 4; ++mt)
        af[mt] = *(const bf16x8*)&As[(mw + mt * 16 + col) * 64 + ks * 32 + quad * 8];
#pragma unroll
      for (int nt = 0; nt < 4; ++nt)
        bfr[nt] = *(const bf16x8*)&Bs[(nw + nt * 16 + col) * 64 + ks * 32 + quad * 8];
#pragma unroll
      for (int mt = 0; mt < 4; ++mt)
#pragma unroll
        for (int nt = 0; nt < 4; ++nt)
          acc[mt][nt] = __builtin_amdgcn_mfma_f32_16x16x32_bf16(
              af[mt], bfr[nt], acc[mt][nt], 0, 0, 0);
    }
    __syncthreads();  // publishes stage(kk+1); all reads of buf done
  }

  const int p = bx / 6;
  const float* bp = (p == 0) ? bq : ((p == 1) ? bk : bv);
  const float kscale = (p == 1) ? 0.18033688011112042f : 1.0f;  // log2(e)/sqrt(64)
  const int bb0 = m0 >> 11, s0 = m0 & 2047;
  if (p < 2) {
#pragma unroll
    for (int nt = 0; nt < 4; nt++) {
      int n = nw + nt * 16 + col;
      float bias = bp[n0 + n - p * 768];
#pragma unroll
      for (int mt = 0; mt < 4; mt++)
#pragma unroll
        for (int r = 0; r < 4; r++) {
          int m = mw + mt * 16 + quad * 4 + r;
          Cs[m * 136 + n] = (bf16_t)((acc[mt][nt][r] + bias) * kscale);
        }
    }
    __syncthreads();
    bf16_t* dst = (p == 0) ? Qo : Ko;
#pragma unroll
    for (int i = 0; i < 8; i++) {
      int idx = i * 256 + tid;
      int m = idx >> 4, c = idx & 15;
      bf16x8 v = *(const bf16x8*)&Cs[m * 136 + c * 8];
      int nn = n0 - p * 768 + c * 8;
      int hq = nn >> 6, hd = nn & 63;
      *(bf16x8*)&dst[(size_t)((bb0 * 12 + hq) * 2048 + s0 + m) * 64 + hd] = v;
    }
  } else {
#pragma unroll
    for (int nt = 0; nt < 4; nt++) {
      int n = nw + nt * 16 + col;
      float bias = bp[n0 + n - 1536];
#pragma unroll
      for (int mt = 0; mt < 4; mt++)
#pragma unroll
        for (int r = 0; r < 4; r++) {
          int m = mw + mt * 16 + quad * 4 + r;
          Cs[n * 136 + m] = (bf16_t)(acc[mt][nt][r] + bias);
        }
    }
    __syncthreads();
#pragma unroll
    for (int i = 0; i < 8; i++) {
      int idx = i * 256 + tid;
      int n = idx >> 4, c = idx & 15;
      bf16x8 v = *(const bf16x8*)&Cs[n * 136 + c * 8];
      int nn = n0 - 1536 + n;
      int hq = nn >> 6, hd = nn & 63;
      *(bf16x8*)&VTo[((size_t)(bb0 * 12 + hq) * 64 + hd) * 2048 + s0 + c * 8] = v;
    }
  }
}

// ---------------------------------------------------------------- K3: attention
// v10 = v7 (best known: LDS-staged, 4-wave, ksplit=2, counted-vmcnt) + T15
// 2-stage software pipeline: QK^T of tile t+1 is computed BEFORE softmax+PV
// of tile t (two sacc register sets, ping-pong via 2-tile-unrolled loop, all
// static indexing). The QK MFMA chain + its ds_reads execute in the matrix/LDS
// pipes while the VALU does exp2/pack of the previous tile -- removing the
// longest serial segment of the per-iteration chain. Round-4/5 lessons kept:
// no extra ksplit (traffic), no per-lane global fragment streaming (scatter).
// Buffers: iter kb reads Kl[(kb+1)%3] (QK) + Vl[kb%3] (PV), stages (kb+2)%3;
// single vmcnt(0)+barrier per iter (issue->drain = one compute body).
__global__ __launch_bounds__(256, 3) void attn(const bf16_t* __restrict__ Q,
                                               const bf16_t* __restrict__ K,
                                               const bf16_t* __restrict__ VT,
                                               float* __restrict__ Op,
                                               float* __restrict__ lp) {
  __shared__ __align__(16) char smem[49152];
  bf16_t* Kl = (bf16_t*)smem;            // [3][64*64], 16B chunks XOR-swz row&7
  bf16_t* Vl = (bf16_t*)(smem + 24576);  // [3][64*64], same swizzle
  const int id = blockIdx.x;             // 0..767
  const int rr0 = id >> 3;               // 0..95
  const int bh = (id & 7) * 3 + (rr0 >> 5);  // XCD id&7 owns 3 consecutive bh
  const int w5 = rr0 & 31;
  const int qt = w5 & 15, sp = w5 >> 4;  // q-tile, key-split half
  const int tid = threadIdx.x, wv = tid >> 6, lane = tid & 63;
  const int lq = lane & 31, half = lane >> 5;
  const int q0 = qt * 128 + wv * 32;

  bf16x8 qf[4];  // B-frags of Q^T (per-lane query = lq), register resident
#pragma unroll
  for (int ks = 0; ks < 4; ++ks)
    qf[ks] = *(const bf16x8*)&Q[(size_t)(bh * 2048 + q0 + lq) * 64 + ks * 16 + half * 8];

  f32x16 oacc[2];  // O^T partial: col=q (lane), rows=d
  for (int i = 0; i < 16; i++) { oacc[0][i] = 0.f; oacc[1][i] = 0.f; }
  float l0 = 0.f, l1 = 0.f, l2 = 0.f, l3 = 0.f;  // partial denominators

  const bf16_t* gK = K + (size_t)bh * 2048 * 64 + (size_t)sp * 1024 * 64;
  const bf16_t* gV = VT + (size_t)bh * 64 * 2048 + sp * 1024;
  const int srow = lane >> 3, scc = lane & 7;
  const int cg = scc ^ srow;  // inverse-swizzled source col (row&7 == srow)
  const bf16_t* gKb = gK + srow * 64 + cg * 8;    // + kb*4096 + ii*512
  const bf16_t* gVb = gV + srow * 2048 + cg * 8;  // + ii*16384 + kb*64
  const int kpart = (wv & 1) * 4;  // waves 0,1 stage K chunks 0-3/4-7; 2,3 V

  auto stage = [&](int kb, int buf) {
    if (wv < 2) {
#pragma unroll
      for (int i = 0; i < 4; i++) {
        int ii = kpart + i;
        gload_lds16(gKb + kb * 4096 + ii * 512, Kl + buf * 4096 + ii * 512);
      }
    } else {
#pragma unroll
      for (int i = 0; i < 4; i++) {
        int ii = kpart + i;
        gload_lds16(gVb + (size_t)ii * 16384 + kb * 64, Vl + buf * 4096 + ii * 512);
      }
    }
  };

  f32x16 sA[2], sB[2];  // ping-pong QK accumulators (static indexing only)

#if __has_builtin(__builtin_amdgcn_permlane32_swap)
#define XHALF(a, b, F, wd)                                              \
  { u32x2 sw_ = __builtin_amdgcn_permlane32_swap(a, b, false, false);   \
    F.u[wd] = sw_.x; F.u[2 + wd] = sw_.y; }
#else
#define XHALF(a, b, F, wd)                                              \
  { uint32_t s_ = half ? (a) : (b);                                     \
    uint32_t rx_ = __shfl_xor(s_, 32);                                  \
    uint32_t ow_ = half ? (b) : (a);                                    \
    F.u[wd] = half ? rx_ : ow_; F.u[2 + wd] = half ? ow_ : rx_; }
#endif

  // S^T[key][q] = K_blk @ Q^T  (K pre-scaled by log2e/8 at projection)
#define QK(bt, S)                                                           \
  {                                                                         \
    for (int i_ = 0; i_ < 16; i_++) { S[0][i_] = 0.f; S[1][i_] = 0.f; }     \
    __builtin_amdgcn_s_setprio(1);                                          \
    _Pragma("unroll")                                                       \
    for (int t_ = 0; t_ < 2; t_++) {                                        \
      const int row_ = t_ * 32 + lq;                                        \
      _Pragma("unroll")                                                     \
      for (int ks_ = 0; ks_ < 4; ++ks_) {                                   \
        bf16x8 kf_ = *(const bf16x8*)&Kl[(bt) * 4096 + row_ * 64 +          \
                                         (((2 * ks_ + half) ^ (row_ & 7)) * 8)]; \
        S[t_] = __builtin_amdgcn_mfma_f32_32x32x16_bf16(kf_, qf[ks_], S[t_], 0, 0, 0); \
      }                                                                     \
    }                                                                       \
    __builtin_amdgcn_s_setprio(0);                                          \
  }

  // softmax (fixed max) + pack + cross-half exchange + PV on Vl[bt]
#define SMPV(bt, S)                                                         \
  {                                                                         \
    _Pragma("unroll")                                                       \
    for (int t_ = 0; t_ < 2; t_++)                                          \
      _Pragma("unroll")                                                     \
      for (int rr_ = 0; rr_ < 16; rr_++) S[t_][rr_] = fexp2(S[t_][rr_]);    \
    _Pragma("unroll")                                                       \
    for (int rr_ = 0; rr_ < 16; rr_ += 4) {                                 \
      l0 += S[0][rr_ + 0] + S[1][rr_ + 0];                                  \
      l1 += S[0][rr_ + 1] + S[1][rr_ + 1];                                  \
      l2 += S[0][rr_ + 2] + S[1][rr_ + 2];                                  \
      l3 += S[0][rr_ + 3] + S[1][rr_ + 3];                                  \
    }                                                                       \
    uint32_t pkq_[2][4][2];                                                 \
    _Pragma("unroll")                                                       \
    for (int t_ = 0; t_ < 2; t_++)                                          \
      _Pragma("unroll")                                                     \
      for (int g_ = 0; g_ < 4; g_++) {                                      \
        pkq_[t_][g_][0] = pk_bf16(S[t_][4 * g_ + 0], S[t_][4 * g_ + 1]);    \
        pkq_[t_][g_][1] = pk_bf16(S[t_][4 * g_ + 2], S[t_][4 * g_ + 3]);    \
      }                                                                     \
    bf16x8 pfrag_[4];                                                       \
    _Pragma("unroll")                                                       \
    for (int t_ = 0; t_ < 2; t_++)                                          \
      _Pragma("unroll")                                                     \
      for (int e_ = 0; e_ < 2; e_++) {                                      \
        union { uint32_t u[4]; bf16x8 v; } F;                               \
        XHALF(pkq_[t_][2 * e_][0], pkq_[t_][2 * e_ + 1][0], F, 0);          \
        XHALF(pkq_[t_][2 * e_][1], pkq_[t_][2 * e_ + 1][1], F, 1);          \
        pfrag_[2 * t_ + e_] = F.v;                                          \
      }                                                                     \
    __builtin_amdgcn_s_setprio(1);                                          \
    _Pragma("unroll")                                                       \
    for (int c_ = 0; c_ < 4; c_++) {                                        \
      _Pragma("unroll")                                                     \
      for (int dt_ = 0; dt_ < 2; dt_++) {                                   \
        const int vr_ = dt_ * 32 + lq;                                      \
        bf16x8 vf_ = *(const bf16x8*)&Vl[(bt) * 4096 + vr_ * 64 +           \
                                         (((2 * c_ + half) ^ (vr_ & 7)) * 8)]; \
        oacc[dt_] = __builtin_amdgcn_mfma_f32_32x32x16_bf16(vf_, pfrag_[c_], oacc[dt_], 0, 0, 0); \
      }                                                                     \
    }                                                                       \
    __builtin_amdgcn_s_setprio(0);                                          \
  }

  // prologue: two tiles staged; QK(0) computed; stage(1) published
  stage(0, 0);
  stage(1, 1);
  asm volatile("s_waitcnt vmcnt(4)" ::: "memory");  // Q + stage(0) done
  __builtin_amdgcn_s_barrier();
  asm volatile("" ::: "memory");
  QK(0, sA);
  asm volatile("s_waitcnt vmcnt(0)" ::: "memory");  // stage(1) done (own)
  __builtin_amdgcn_s_barrier();                     // cross-wave
  asm volatile("" ::: "memory");

  int b_pv = 0, b_qk = 1, b_st = 2;
  for (int kb = 0; kb < 16; kb += 2) {
    // even tile: consume sA, prefetch-compute into sB
    if (kb < 14) stage(kb + 2, b_st);
    if (kb < 15) QK(b_qk, sB);
    SMPV(b_pv, sA);
    asm volatile("s_waitcnt vmcnt(0)" ::: "memory");
    __builtin_amdgcn_s_barrier();
    asm volatile("" ::: "memory");
    b_pv = b_qk; b_qk = b_st; b_st = (b_st == 2) ? 0 : b_st + 1;
    // odd tile: consume sB, prefetch-compute into sA
    if (kb + 1 < 14) stage(kb + 3, b_st);
    if (kb + 1 < 15) QK(b_qk, sA);
    SMPV(b_pv, sB);
    asm volatile("s_waitcnt vmcnt(0)" ::: "memory");
    __builtin_amdgcn_s_barrier();
    asm volatile("" ::: "memory");
    b_pv = b_qk; b_qk = b_st; b_st = (b_st == 2) ? 0 : b_st + 1;
  }

#undef QK
#undef SMPV
#undef XHALF

  // epilogue: partial l + unnormalized partial O^T -> Op[q][d] rows
  float l_own = (l0 + l1) + (l2 + l3);
  float l_tot = l_own + __shfl_xor(l_own, 32);
  if (half == 0) lp[((size_t)sp * 24 + bh) * 2048 + q0 + lq] = l_tot;
  // final in-loop barrier already ordered all K/V reads; smem -> 4x8KB scratch
  float* Of = (float*)smem + wv * 2048;
#pragma unroll
  for (int dt = 0; dt < 2; dt++)
#pragma unroll
    for (int rr = 0; rr < 16; rr++) {
      int d = dt * 32 + (rr & 3) + 8 * (rr >> 2) + 4 * half;
      int g = d >> 2, wd = d & 3;
      Of[lq * 64 + ((g ^ (lq & 15)) * 4) + wd] = oacc[dt][rr];
    }
  float* ob = Op + (((size_t)sp * 24 + bh) * 2048 + q0) * 64;
#pragma unroll
  for (int i = 0; i < 8; i++) {
    int idx = i * 64 + lane;
    int qq = idx >> 4, c = idx & 15;
    f32x4 v = *(f32x4*)&Of[qq * 64 + ((c ^ (qq & 15)) * 4)];
    *(f32x4*)&ob[(size_t)qq * 64 + c * 4] = v;
  }
}

// ------------------------------------------------- K4: combine split-K partials
// out[b][q][h*64+d] = (Op0 + Op1) / (l0 + l1), with head-merge transpose.
__global__ __launch_bounds__(256) void combine(const float* __restrict__ Op,
                                               const float* __restrict__ lp,
                                               float* __restrict__ out) {
  int g = blockIdx.x * 256 + threadIdx.x;  // over 24*2048*16 = 786432
  int bh = g >> 15;
  int rem = g & 32767;
  int q = rem >> 4, c = rem & 15;
  const size_t plane = (size_t)24 * 2048 * 64;
  size_t o0 = ((size_t)bh * 2048 + q) * 64 + c * 4;
  f32x4 a = *(const f32x4*)&Op[o0];
  f32x4 b2 = *(const f32x4*)&Op[plane + o0];
  float l = lp[bh * 2048 + q] + lp[24 * 2048 + bh * 2048 + q];
  float inv = 1.0f / l;
  int b = bh / 12, head = bh % 12;
  f32x4 r;
#pragma unroll
  for (int j = 0; j < 4; j++) r[j] = (a[j] + b2[j]) * inv;
  *(f32x4*)&out[((size_t)b * 2048 + q) * 768 + head * 64 + c * 4] = r;
}

// -------------------------------------------------------------------- launcher
extern "C" void kernel_launch(void* const* d_in, const int* in_sizes, int n_in,
                              void* d_out, int out_size, void* d_ws, size_t ws_size,
                              hipStream_t stream) {
  const float* hs = (const float*)d_in[0];
  const float* Wq = (const float*)d_in[1];
  const float* bq = (const float*)d_in[2];
  const float* Wk = (const float*)d_in[3];
  const float* bk = (const float*)d_in[4];
  const float* Wv = (const float*)d_in[5];
  const float* bv = (const float*)d_in[6];
  float* out = (float*)d_out;

  char* w = (char*)d_ws;
  bf16_t* hsb = (bf16_t*)w; w += (size_t)4096 * 768 * 2;
  bf16_t* wtb = (bf16_t*)w; w += (size_t)2304 * 768 * 2;
  bf16_t* Qb  = (bf16_t*)w; w += (size_t)24 * 2048 * 64 * 2;
  bf16_t* Kb  = (bf16_t*)w; w += (size_t)24 * 2048 * 64 * 2;
  bf16_t* VTb = (bf16_t*)w; w += (size_t)24 * 2048 * 64 * 2;
  float* Opw  = (float*)w;  w += (size_t)2 * 24 * 2048 * 64 * 4;  // 25.2 MB
  float* lpw  = (float*)w;                                        // 0.39 MB

  hipLaunchKernelGGL(cvt_hs, dim3(3072), dim3(256), 0, stream, hs, hsb);
  hipLaunchKernelGGL(cvt_w, dim3(72, 24), dim3(256), 0, stream, Wq, Wk, Wv, wtb);
  hipLaunchKernelGGL(gemm_qkv, dim3(18, 32), dim3(256), 0, stream, hsb, wtb, bq,
                     bk, bv, Qb, Kb, VTb);
  hipLaunchKernelGGL(attn, dim3(768), dim3(256), 0, stream, Qb, Kb, VTb, Opw, lpw);
  hipLaunchKernelGGL(combine, dim3(3072), dim3(256), 0, stream, Opw, lpw, out);
}

// Round 7
// 154.538 us; speedup vs baseline: 1.3734x; 1.1798x over previous
//
#include <hip/hip_runtime.h>
#include <stdint.h>

typedef __bf16 bf16_t;
typedef __bf16 bf16x8 __attribute__((ext_vector_type(8)));
typedef float f32x4 __attribute__((ext_vector_type(4)));
typedef float f32x16 __attribute__((ext_vector_type(16)));
typedef unsigned int u32x2 __attribute__((ext_vector_type(2)));

#define DEV __device__ __forceinline__

DEV void gload_lds16(const void* g, void* lds) {
  __builtin_amdgcn_global_load_lds(
      (const __attribute__((address_space(1))) uint32_t*)g,
      (__attribute__((address_space(3))) uint32_t*)lds, 16, 0, 0);
}

DEV float fexp2(float x) {
#if __has_builtin(__builtin_amdgcn_exp2f)
  return __builtin_amdgcn_exp2f(x);
#else
  return exp2f(x);
#endif
}

DEV uint32_t pk_bf16(float a, float b) {
  uint32_t lo = (uint32_t)__builtin_bit_cast(uint16_t, (bf16_t)a);
  uint32_t hi = (uint32_t)__builtin_bit_cast(uint16_t, (bf16_t)b);
  return lo | (hi << 16);
}

// ---------------------------------------------------------------- K0: hs -> bf16
__global__ __launch_bounds__(256) void cvt_hs(const float* __restrict__ x,
                                              bf16_t* __restrict__ y) {
  int i = blockIdx.x * 256 + threadIdx.x;
  float4 v = ((const float4*)x)[i];
  ((uint2*)y)[i] = make_uint2(pk_bf16(v.x, v.y), pk_bf16(v.z, v.w));
}

// ------------------------------------------- K1: W[k][n] (x3) -> WT[n][k] bf16
__global__ __launch_bounds__(256) void cvt_w(const float* __restrict__ Wq,
                                             const float* __restrict__ Wk,
                                             const float* __restrict__ Wv,
                                             bf16_t* __restrict__ WT) {
  __shared__ float T[32][36];
  const int bx = blockIdx.x;   // n tile 0..71 (over 2304)
  const int by = blockIdx.y;   // k tile 0..23 (over 768)
  const int p = bx / 24;
  const float* W = (p == 0) ? Wq : ((p == 1) ? Wk : Wv);
  const int n0 = bx * 32, nn0 = n0 - p * 768, k0 = by * 32;
  const int t = threadIdx.x;
  {
    int r = t >> 3, c4 = (t & 7) * 4;
    float4 v = *(const float4*)&W[(size_t)(k0 + r) * 768 + nn0 + c4];
    T[r][c4 + 0] = v.x; T[r][c4 + 1] = v.y; T[r][c4 + 2] = v.z; T[r][c4 + 3] = v.w;
  }
  __syncthreads();
  {
    int nr = t >> 3, kc = (t & 7) * 4;
    uint32_t lo = pk_bf16(T[kc + 0][nr], T[kc + 1][nr]);
    uint32_t hi = pk_bf16(T[kc + 2][nr], T[kc + 3][nr]);
    *(uint2*)&WT[(size_t)(n0 + nr) * 768 + k0 + kc] = make_uint2(lo, hi);
  }
}

// ------------------------------------------------- K2: C[4096,2304] = A @ W (+b)
// K-projection output is pre-scaled by log2(e)/8 (softmax scale folded in).
// v3: BK=32 + T2 XOR-swizzle. Round-2 evidence: MfmaUtil 11.7%, 5.4M LDS bank
// conflicts (lanes 0-15 read rows at 128B stride -> banks 0-3, 16-way), and
// 64KB LDS capped occupancy at 2 blocks/CU with a 576/512 dispatch tail.
// Now: per-buffer A+B = 16KB, dbuf = 32KB; Cs union (34816B) -> LDS 34816 ->
// 4 blocks/CU = 16 waves/CU, grid 576 fully resident (no tail). Staging is
// pre-swizzled at the GLOBAL source (m173 pattern, same as attn): LDS slot
// (row, s) holds global 16B-chunk s^(row&3); reads XOR back -> ~2-way (free).
// K-accumulation order is bit-identical to BK=64 (same K=32 MFMA sequence).
__global__ __launch_bounds__(256) void gemm_qkv(
    const bf16_t* __restrict__ A, const bf16_t* __restrict__ Wt,
    const float* __restrict__ bq, const float* __restrict__ bk,
    const float* __restrict__ bv, bf16_t* __restrict__ Qo,
    bf16_t* __restrict__ Ko, bf16_t* __restrict__ VTo) {
  __shared__ __align__(16) char smem[34816];  // 2 x (As 8K + Bs 8K) | Cs 128x136
  bf16_t* Cs = (bf16_t*)smem;  // epilogue scratch (union with staging buffers)
  const int bx = blockIdx.x;  // 0..17 (n)
  const int by = blockIdx.y;  // 0..31 (m)
  const int m0 = by * 128, n0 = bx * 128;
  const int tid = threadIdx.x, w = tid >> 6, lane = tid & 63;
  const int mw = (w & 1) * 64, nw = (w >> 1) * 64;
  const int quad = lane >> 4, col = lane & 15;

  f32x4 acc[4][4];
  for (int i = 0; i < 4; i++)
    for (int j = 0; j < 4; j++) acc[i][j] = (f32x4){0.f, 0.f, 0.f, 0.f};

  // staging: 8 chunks of 1KB per matrix (chunk ci = rows ci*16..+15, 64B wide);
  // wave w stages chunks {2w, 2w+1} of A and of B.
  // lane l in chunk: row-in-chunk cr = l>>2; source 16B-slot gc = (l&3)^(cr&3)
  // (XOR by row&3 -- chunk row parity == global row parity since 16 | rowbase).
  const int cr = lane >> 2;
  const int gcs = (lane & 3) ^ (cr & 3);
  const bf16_t* ag = A + (size_t)(m0 + 2 * w * 16 + cr) * 768 + gcs * 8;
  const bf16_t* bg = Wt + (size_t)(n0 + 2 * w * 16 + cr) * 768 + gcs * 8;

  auto stageg = [&](int kk, int bf) {
    const int k0 = kk * 32;
    bf16_t* dA = (bf16_t*)(smem + bf * 16384) + 2 * w * 512;
    bf16_t* dB = (bf16_t*)(smem + bf * 16384 + 8192) + 2 * w * 512;
#pragma unroll
    for (int i = 0; i < 2; i++) {
      gload_lds16(ag + (size_t)i * 16 * 768 + k0, dA + i * 512);
      gload_lds16(bg + (size_t)i * 16 * 768 + k0, dB + i * 512);
    }
  };

  stageg(0, 0);
  __syncthreads();  // one exposed drain at prologue only

  for (int kk = 0; kk < 24; ++kk) {
    const int bf = kk & 1;
    if (kk < 23) stageg(kk + 1, bf ^ 1);
    __builtin_amdgcn_sched_barrier(0);  // pin load issue ahead of compute
    const bf16_t* As = (const bf16_t*)(smem + bf * 16384);
    const bf16_t* Bs = (const bf16_t*)(smem + bf * 16384 + 8192);
    bf16x8 af[4], bfr[4];
#pragma unroll
    for (int mt = 0; mt < 4; ++mt) {
      int row = mw + mt * 16 + col;
      af[mt] = *(const bf16x8*)&As[row * 32 + ((quad ^ (row & 3)) * 8)];
    }
#pragma unroll
    for (int nt = 0; nt < 4; ++nt) {
      int row = nw + nt * 16 + col;
      bfr[nt] = *(const bf16x8*)&Bs[row * 32 + ((quad ^ (row & 3)) * 8)];
    }
#pragma unroll
    for (int mt = 0; mt < 4; ++mt)
#pragma unroll
      for (int nt = 0; nt < 4; ++nt)
        acc[mt][nt] = __builtin_amdgcn_mfma_f32_16x16x32_bf16(
            af[mt], bfr[nt], acc[mt][nt], 0, 0, 0);
    __syncthreads();  // publishes stage(kk+1); all reads of buf done
  }

  const int p = bx / 6;
  const float* bp = (p == 0) ? bq : ((p == 1) ? bk : bv);
  const float kscale = (p == 1) ? 0.18033688011112042f : 1.0f;  // log2(e)/sqrt(64)
  const int bb0 = m0 >> 11, s0 = m0 & 2047;
  if (p < 2) {
#pragma unroll
    for (int nt = 0; nt < 4; nt++) {
      int n = nw + nt * 16 + col;
      float bias = bp[n0 + n - p * 768];
#pragma unroll
      for (int mt = 0; mt < 4; mt++)
#pragma unroll
        for (int r = 0; r < 4; r++) {
          int m = mw + mt * 16 + quad * 4 + r;
          Cs[m * 136 + n] = (bf16_t)((acc[mt][nt][r] + bias) * kscale);
        }
    }
    __syncthreads();
    bf16_t* dst = (p == 0) ? Qo : Ko;
#pragma unroll
    for (int i = 0; i < 8; i++) {
      int idx = i * 256 + tid;
      int m = idx >> 4, c = idx & 15;
      bf16x8 v = *(const bf16x8*)&Cs[m * 136 + c * 8];
      int nn = n0 - p * 768 + c * 8;
      int hq = nn >> 6, hd = nn & 63;
      *(bf16x8*)&dst[(size_t)((bb0 * 12 + hq) * 2048 + s0 + m) * 64 + hd] = v;
    }
  } else {
#pragma unroll
    for (int nt = 0; nt < 4; nt++) {
      int n = nw + nt * 16 + col;
      float bias = bp[n0 + n - 1536];
#pragma unroll
      for (int mt = 0; mt < 4; mt++)
#pragma unroll
        for (int r = 0; r < 4; r++) {
          int m = mw + mt * 16 + quad * 4 + r;
          Cs[n * 136 + m] = (bf16_t)(acc[mt][nt][r] + bias);
        }
    }
    __syncthreads();
#pragma unroll
    for (int i = 0; i < 8; i++) {
      int idx = i * 256 + tid;
      int n = idx >> 4, c = idx & 15;
      bf16x8 v = *(const bf16x8*)&Cs[n * 136 + c * 8];
      int nn = n0 - 1536 + n;
      int hq = nn >> 6, hd = nn & 63;
      *(bf16x8*)&VTo[((size_t)(bb0 * 12 + hq) * 64 + hd) * 2048 + s0 + c * 8] = v;
    }
  }
}

// ---------------------------------------------------------------- K3: attention
// v7 (round-3 best, 43.7 us) VERBATIM. Three structural variants all lost:
// ksplit=4 occupancy push (+HBM traffic, 2x slower), register-direct streaming
// (scatter-gather VMEM, 2.4x slower), QK-ahead ping-pong (acc set spilled to
// scratch: VGPR 84 w/ +64 regs live state, WRITE +57MB). Do not restructure.
__global__ __launch_bounds__(256, 3) void attn(const bf16_t* __restrict__ Q,
                                               const bf16_t* __restrict__ K,
                                               const bf16_t* __restrict__ VT,
                                               float* __restrict__ Op,
                                               float* __restrict__ lp) {
  __shared__ __align__(16) char smem[49152];
  bf16_t* Kl = (bf16_t*)smem;            // [3][64*64], XOR-swizzled by row&7
  bf16_t* Vl = (bf16_t*)(smem + 24576);  // [3][64*64], same swizzle
  const int id = blockIdx.x;             // 0..767
  const int rr0 = id >> 3;               // 0..95
  const int bh = (id & 7) * 3 + (rr0 >> 5);  // XCD id&7 owns 3 consecutive bh
  const int w5 = rr0 & 31;
  const int qt = w5 & 15, sp = w5 >> 4;  // q-tile, key-split half
  const int tid = threadIdx.x, wv = tid >> 6, lane = tid & 63;
  const int lq = lane & 31, half = lane >> 5;
  const int q0 = qt * 128 + wv * 32;

  bf16x8 qf[4];  // B-frags of Q^T (per-lane query = lq), register resident
#pragma unroll
  for (int ks = 0; ks < 4; ++ks)
    qf[ks] = *(const bf16x8*)&Q[(size_t)(bh * 2048 + q0 + lq) * 64 + ks * 16 + half * 8];

  f32x16 oacc[2];  // O^T partial: col=q (lane), rows=d
  for (int i = 0; i < 16; i++) { oacc[0][i] = 0.f; oacc[1][i] = 0.f; }
  float l0 = 0.f, l1 = 0.f, l2 = 0.f, l3 = 0.f;  // partial denominators

  const bf16_t* gK = K + (size_t)bh * 2048 * 64 + (size_t)sp * 1024 * 64;
  const bf16_t* gV = VT + (size_t)bh * 64 * 2048 + sp * 1024;
  const int srow = lane >> 3, scc = lane & 7;
  const int cg = scc ^ srow;  // inverse-swizzled source col (row&7 == srow)
  const bf16_t* gKb = gK + srow * 64 + cg * 8;    // + kb*4096 + ii*512
  const bf16_t* gVb = gV + srow * 2048 + cg * 8;  // + ii*16384 + kb*64
  const int kpart = (wv & 1) * 4;  // waves 0,1 stage K chunks 0-3/4-7; 2,3 V

  auto stage = [&](int kb, int buf) {
    if (wv < 2) {
#pragma unroll
      for (int i = 0; i < 4; i++) {
        int ii = kpart + i;
        gload_lds16(gKb + kb * 4096 + ii * 512, Kl + buf * 4096 + ii * 512);
      }
    } else {
#pragma unroll
      for (int i = 0; i < 4; i++) {
        int ii = kpart + i;
        gload_lds16(gVb + (size_t)ii * 16384 + kb * 64, Vl + buf * 4096 + ii * 512);
      }
    }
  };

  stage(0, 0);
  stage(1, 1);
  asm volatile("s_waitcnt vmcnt(4)" ::: "memory");  // buf0 (+Q) done; buf1 flying
  __builtin_amdgcn_s_barrier();
  asm volatile("" ::: "memory");

  int bb = 0, rb = 2;
  for (int kb = 0; kb < 16; ++kb) {
    if (kb < 14) stage(kb + 2, rb);  // 2-deep prefetch, in flight across barriers

    // S^T[key][q] = K_blk @ Q^T   (K pre-scaled by log2e/8 at projection)
    f32x16 sacc[2];
    for (int i = 0; i < 16; i++) { sacc[0][i] = 0.f; sacc[1][i] = 0.f; }
    __builtin_amdgcn_s_setprio(1);
#pragma unroll
    for (int t = 0; t < 2; t++) {
      const int row = t * 32 + lq;
#pragma unroll
      for (int ks = 0; ks < 4; ++ks) {
        bf16x8 kf = *(const bf16x8*)&Kl[bb * 4096 + row * 64 + (((2 * ks + half) ^ (row & 7)) * 8)];
        sacc[t] = __builtin_amdgcn_mfma_f32_32x32x16_bf16(kf, qf[ks], sacc[t], 0, 0, 0);
      }
    }
    __builtin_amdgcn_s_setprio(0);

    // P = exp2(S) (fixed max), l in 4 partial chains
#pragma unroll
    for (int t = 0; t < 2; t++)
#pragma unroll
      for (int rr = 0; rr < 16; rr++) sacc[t][rr] = fexp2(sacc[t][rr]);
#pragma unroll
    for (int rr = 0; rr < 16; rr += 4) {
      l0 += sacc[0][rr + 0] + sacc[1][rr + 0];
      l1 += sacc[0][rr + 1] + sacc[1][rr + 1];
      l2 += sacc[0][rr + 2] + sacc[1][rr + 2];
      l3 += sacc[0][rr + 3] + sacc[1][rr + 3];
    }

    // pack quads: pkq[t][g] = keys t*32 + 8g + 4*half + {0..3}, as 2x u32
    uint32_t pkq[2][4][2];
#pragma unroll
    for (int t = 0; t < 2; t++)
#pragma unroll
      for (int g = 0; g < 4; g++) {
        pkq[t][g][0] = pk_bf16(sacc[t][4 * g + 0], sacc[t][4 * g + 1]);
        pkq[t][g][1] = pk_bf16(sacc[t][4 * g + 2], sacc[t][4 * g + 3]);
      }

    // cross-half exchange -> B-operand frags via permlane32_swap
    bf16x8 pfrag[4];
#pragma unroll
    for (int t = 0; t < 2; t++)
#pragma unroll
      for (int e = 0; e < 2; e++) {
        union { uint32_t u[4]; bf16x8 v; } F;
#pragma unroll
        for (int wd = 0; wd < 2; wd++) {
#if __has_builtin(__builtin_amdgcn_permlane32_swap)
          u32x2 sw = __builtin_amdgcn_permlane32_swap(pkq[t][2 * e][wd],
                                                      pkq[t][2 * e + 1][wd],
                                                      false, false);
          F.u[wd] = sw.x;
          F.u[2 + wd] = sw.y;
#else
          uint32_t s = half ? pkq[t][2 * e][wd] : pkq[t][2 * e + 1][wd];
          uint32_t rx = __shfl_xor(s, 32);
          uint32_t ow = half ? pkq[t][2 * e + 1][wd] : pkq[t][2 * e][wd];
          F.u[wd] = half ? rx : ow;
          F.u[2 + wd] = half ? ow : rx;
#endif
        }
        pfrag[2 * t + e] = F.v;
      }

    // O^T += V^T @ P^T  (A = V frags from LDS, B = pfrag)
    __builtin_amdgcn_s_setprio(1);
#pragma unroll
    for (int c = 0; c < 4; c++) {
#pragma unroll
      for (int dt = 0; dt < 2; dt++) {
        const int vr = dt * 32 + lq;
        bf16x8 vf = *(const bf16x8*)&Vl[bb * 4096 + vr * 64 + (((2 * c + half) ^ (vr & 7)) * 8)];
        oacc[dt] = __builtin_amdgcn_mfma_f32_32x32x16_bf16(vf, pfrag[c], oacc[dt], 0, 0, 0);
      }
    }
    __builtin_amdgcn_s_setprio(0);

    // counted wait: keep newest stage batch (4 loads/wave) in flight
    if (kb < 14) {
      asm volatile("s_waitcnt vmcnt(4)" ::: "memory");
    } else if (kb == 14) {
      asm volatile("s_waitcnt vmcnt(0)" ::: "memory");
    }
    if (kb < 15) {
      __builtin_amdgcn_s_barrier();
      asm volatile("" ::: "memory");
    }
    bb = (bb == 2) ? 0 : bb + 1;
    rb = (rb == 2) ? 0 : rb + 1;
  }

  // epilogue: partial l + unnormalized partial O^T -> Op[q][d] rows
  float l_own = (l0 + l1) + (l2 + l3);
  float l_tot = l_own + __shfl_xor(l_own, 32);
  __syncthreads();  // all K/V reads done; smem becomes 4x 8KB f32 scratch
  float* Of = (float*)smem + wv * 2048;
#pragma unroll
  for (int dt = 0; dt < 2; dt++)
#pragma unroll
    for (int rr = 0; rr < 16; rr++) {
      int d = dt * 32 + (rr & 3) + 8 * (rr >> 2) + 4 * half;
      int g = d >> 2, wd = d & 3;
      Of[lq * 64 + ((g ^ (lq & 15)) * 4) + wd] = oacc[dt][rr];
    }
  if (half == 0) lp[((size_t)sp * 24 + bh) * 2048 + q0 + lq] = l_tot;
  float* ob = Op + (((size_t)sp * 24 + bh) * 2048 + q0) * 64;
#pragma unroll
  for (int i = 0; i < 8; i++) {
    int idx = i * 64 + lane;
    int qq = idx >> 4, c = idx & 15;
    f32x4 v = *(f32x4*)&Of[qq * 64 + ((c ^ (qq & 15)) * 4)];
    *(f32x4*)&ob[(size_t)qq * 64 + c * 4] = v;
  }
}

// ------------------------------------------------- K4: combine split-K partials
// out[b][q][h*64+d] = (Op0 + Op1) / (l0 + l1), with head-merge transpose.
__global__ __launch_bounds__(256) void combine(const float* __restrict__ Op,
                                               const float* __restrict__ lp,
                                               float* __restrict__ out) {
  int g = blockIdx.x * 256 + threadIdx.x;  // over 24*2048*16 = 786432
  int bh = g >> 15;
  int rem = g & 32767;
  int q = rem >> 4, c = rem & 15;
  const size_t plane = (size_t)24 * 2048 * 64;
  size_t o0 = ((size_t)bh * 2048 + q) * 64 + c * 4;
  f32x4 a = *(const f32x4*)&Op[o0];
  f32x4 b2 = *(const f32x4*)&Op[plane + o0];
  float l = lp[bh * 2048 + q] + lp[24 * 2048 + bh * 2048 + q];
  float inv = 1.0f / l;
  int b = bh / 12, head = bh % 12;
  f32x4 r;
#pragma unroll
  for (int j = 0; j < 4; j++) r[j] = (a[j] + b2[j]) * inv;
  *(f32x4*)&out[((size_t)b * 2048 + q) * 768 + head * 64 + c * 4] = r;
}

// -------------------------------------------------------------------- launcher
extern "C" void kernel_launch(void* const* d_in, const int* in_sizes, int n_in,
                              void* d_out, int out_size, void* d_ws, size_t ws_size,
                              hipStream_t stream) {
  const float* hs = (const float*)d_in[0];
  const float* Wq = (const float*)d_in[1];
  const float* bq = (const float*)d_in[2];
  const float* Wk = (const float*)d_in[3];
  const float* bk = (const float*)d_in[4];
  const float* Wv = (const float*)d_in[5];
  const float* bv = (const float*)d_in[6];
  float* out = (float*)d_out;

  char* w = (char*)d_ws;
  bf16_t* hsb = (bf16_t*)w; w += (size_t)4096 * 768 * 2;
  bf16_t* wtb = (bf16_t*)w; w += (size_t)2304 * 768 * 2;
  bf16_t* Qb  = (bf16_t*)w; w += (size_t)24 * 2048 * 64 * 2;
  bf16_t* Kb  = (bf16_t*)w; w += (size_t)24 * 2048 * 64 * 2;
  bf16_t* VTb = (bf16_t*)w; w += (size_t)24 * 2048 * 64 * 2;
  float* Opw  = (float*)w;  w += (size_t)2 * 24 * 2048 * 64 * 4;  // 25.2 MB
  float* lpw  = (float*)w;                                        // 0.39 MB

  hipLaunchKernelGGL(cvt_hs, dim3(3072), dim3(256), 0, stream, hs, hsb);
  hipLaunchKernelGGL(cvt_w, dim3(72, 24), dim3(256), 0, stream, Wq, Wk, Wv, wtb);
  hipLaunchKernelGGL(gemm_qkv, dim3(18, 32), dim3(256), 0, stream, hsb, wtb, bq,
                     bk, bv, Qb, Kb, VTb);
  hipLaunchKernelGGL(attn, dim3(768), dim3(256), 0, stream, Qb, Kb, VTb, Opw, lpw);
  hipLaunchKernelGGL(combine, dim3(3072), dim3(256), 0, stream, Opw, lpw, out);
}

// Round 8
// 148.010 us; speedup vs baseline: 1.4340x; 1.0441x over previous
//
#include <hip/hip_runtime.h>
#include <stdint.h>

typedef __bf16 bf16_t;
typedef __bf16 bf16x8 __attribute__((ext_vector_type(8)));
typedef float f32x4 __attribute__((ext_vector_type(4)));
typedef float f32x16 __attribute__((ext_vector_type(16)));
typedef unsigned int u32x2 __attribute__((ext_vector_type(2)));

#define DEV __device__ __forceinline__

DEV void gload_lds16(const void* g, void* lds) {
  __builtin_amdgcn_global_load_lds(
      (const __attribute__((address_space(1))) uint32_t*)g,
      (__attribute__((address_space(3))) uint32_t*)lds, 16, 0, 0);
}

DEV float fexp2(float x) {
#if __has_builtin(__builtin_amdgcn_exp2f)
  return __builtin_amdgcn_exp2f(x);
#else
  return exp2f(x);
#endif
}

DEV uint32_t pk_bf16(float a, float b) {
  uint32_t lo = (uint32_t)__builtin_bit_cast(uint16_t, (bf16_t)a);
  uint32_t hi = (uint32_t)__builtin_bit_cast(uint16_t, (bf16_t)b);
  return lo | (hi << 16);
}

// ---------------------------------------------------------------- K0: hs -> bf16
__global__ __launch_bounds__(256) void cvt_hs(const float* __restrict__ x,
                                              bf16_t* __restrict__ y) {
  int i = blockIdx.x * 256 + threadIdx.x;
  float4 v = ((const float4*)x)[i];
  ((uint2*)y)[i] = make_uint2(pk_bf16(v.x, v.y), pk_bf16(v.z, v.w));
}

// ------------------------------------------- K1: W[k][n] (x3) -> WT[n][k] bf16
__global__ __launch_bounds__(256) void cvt_w(const float* __restrict__ Wq,
                                             const float* __restrict__ Wk,
                                             const float* __restrict__ Wv,
                                             bf16_t* __restrict__ WT) {
  __shared__ float T[32][36];
  const int bx = blockIdx.x;   // n tile 0..71 (over 2304)
  const int by = blockIdx.y;   // k tile 0..23 (over 768)
  const int p = bx / 24;
  const float* W = (p == 0) ? Wq : ((p == 1) ? Wk : Wv);
  const int n0 = bx * 32, nn0 = n0 - p * 768, k0 = by * 32;
  const int t = threadIdx.x;
  {
    int r = t >> 3, c4 = (t & 7) * 4;
    float4 v = *(const float4*)&W[(size_t)(k0 + r) * 768 + nn0 + c4];
    T[r][c4 + 0] = v.x; T[r][c4 + 1] = v.y; T[r][c4 + 2] = v.z; T[r][c4 + 3] = v.w;
  }
  __syncthreads();
  {
    int nr = t >> 3, kc = (t & 7) * 4;
    uint32_t lo = pk_bf16(T[kc + 0][nr], T[kc + 1][nr]);
    uint32_t hi = pk_bf16(T[kc + 2][nr], T[kc + 3][nr]);
    *(uint2*)&WT[(size_t)(n0 + nr) * 768 + k0 + kc] = make_uint2(lo, hi);
  }
}

// ------------------------------------------------- K2: C[4096,2304] = A @ W (+b)
// K-projection output is pre-scaled by log2(e)/8 (softmax scale folded in).
// v4 = v2 (BK=64 dbuf, round-3 win) + T2 XOR-swizzle ONLY. Round-7 evidence:
// v3's BK=32 halved MFMA-per-barrier while doubling barrier count -> net -7us;
// the swizzle itself targets the measured 5.4M 16-way ds_read conflicts
// (lanes 0-15 read rows at 128B stride -> same banks). Staging pre-swizzles
// the GLOBAL source chunk ((l&7)^((l>>3)&7)) with a linear LDS dest (required
// by global_load_lds); reads XOR the chunk index by row&7 -> ~2-way (free).
// MFMA sequence and K-accumulation order bit-identical to v2.
__global__ __launch_bounds__(256) void gemm_qkv(
    const bf16_t* __restrict__ A, const bf16_t* __restrict__ Wt,
    const float* __restrict__ bq, const float* __restrict__ bk,
    const float* __restrict__ bv, bf16_t* __restrict__ Qo,
    bf16_t* __restrict__ Ko, bf16_t* __restrict__ VTo) {
  __shared__ __align__(16) char smem[65536];  // 2 x (As 16K + Bs 16K); Cs union
  bf16_t* Cs = (bf16_t*)smem;  // 128x136 epilogue scratch
  const int bx = blockIdx.x;  // 0..17 (n)
  const int by = blockIdx.y;  // 0..31 (m)
  const int m0 = by * 128, n0 = bx * 128;
  const int tid = threadIdx.x, w = tid >> 6, lane = tid & 63;
  const int mw = (w & 1) * 64, nw = (w >> 1) * 64;
  const int quad = lane >> 4, col = lane & 15;

  f32x4 acc[4][4];
  for (int i = 0; i < 4; i++)
    for (int j = 0; j < 4; j++) acc[i][j] = (f32x4){0.f, 0.f, 0.f, 0.f};

  // stage: wave w owns rows w*32..+31; lane l -> row w*32+(l>>3), LDS slot l&7.
  // Pre-swizzled source chunk: (l&7) ^ (row&7) = (l&7) ^ ((l>>3)&7).
  const int srow = w * 32 + (lane >> 3);
  const int scol = ((lane & 7) ^ ((lane >> 3) & 7)) * 8;
  const bf16_t* ag = A + (size_t)(m0 + srow) * 768 + scol;
  const bf16_t* bg = Wt + (size_t)(n0 + srow) * 768 + scol;

  auto stageg = [&](int kk, int bf) {
    const int k0 = kk * 64;
    bf16_t* dA = (bf16_t*)(smem + bf * 32768) + (w * 32) * 64;
    bf16_t* dB = (bf16_t*)(smem + bf * 32768 + 16384) + (w * 32) * 64;
#pragma unroll
    for (int i = 0; i < 4; i++) {
      gload_lds16(ag + (size_t)i * 8 * 768 + k0, dA + i * 8 * 64);
      gload_lds16(bg + (size_t)i * 8 * 768 + k0, dB + i * 8 * 64);
    }
  };

  stageg(0, 0);
  __syncthreads();  // one exposed drain at prologue only

  for (int kk = 0; kk < 12; ++kk) {
    const int bf = kk & 1;
    if (kk < 11) stageg(kk + 1, bf ^ 1);
    __builtin_amdgcn_sched_barrier(0);  // pin load issue ahead of compute
    const bf16_t* As = (const bf16_t*)(smem + bf * 32768);
    const bf16_t* Bs = (const bf16_t*)(smem + bf * 32768 + 16384);
#pragma unroll
    for (int ks = 0; ks < 2; ++ks) {
      bf16x8 af[4], bfr[4];
#pragma unroll
      for (int mt = 0; mt < 4; ++mt) {
        int row = mw + mt * 16 + col;
        af[mt] = *(const bf16x8*)&As[row * 64 + (((ks * 4 + quad) ^ (row & 7)) * 8)];
      }
#pragma unroll
      for (int nt = 0; nt < 4; ++nt) {
        int row = nw + nt * 16 + col;
        bfr[nt] = *(const bf16x8*)&Bs[row * 64 + (((ks * 4 + quad) ^ (row & 7)) * 8)];
      }
#pragma unroll
      for (int mt = 0; mt < 4; ++mt)
#pragma unroll
        for (int nt = 0; nt < 4; ++nt)
          acc[mt][nt] = __builtin_amdgcn_mfma_f32_16x16x32_bf16(
              af[mt], bfr[nt], acc[mt][nt], 0, 0, 0);
    }
    __syncthreads();  // publishes stage(kk+1); all reads of buf done
  }

  const int p = bx / 6;
  const float* bp = (p == 0) ? bq : ((p == 1) ? bk : bv);
  const float kscale = (p == 1) ? 0.18033688011112042f : 1.0f;  // log2(e)/sqrt(64)
  const int bb0 = m0 >> 11, s0 = m0 & 2047;
  if (p < 2) {
#pragma unroll
    for (int nt = 0; nt < 4; nt++) {
      int n = nw + nt * 16 + col;
      float bias = bp[n0 + n - p * 768];
#pragma unroll
      for (int mt = 0; mt < 4; mt++)
#pragma unroll
        for (int r = 0; r < 4; r++) {
          int m = mw + mt * 16 + quad * 4 + r;
          Cs[m * 136 + n] = (bf16_t)((acc[mt][nt][r] + bias) * kscale);
        }
    }
    __syncthreads();
    bf16_t* dst = (p == 0) ? Qo : Ko;
#pragma unroll
    for (int i = 0; i < 8; i++) {
      int idx = i * 256 + tid;
      int m = idx >> 4, c = idx & 15;
      bf16x8 v = *(const bf16x8*)&Cs[m * 136 + c * 8];
      int nn = n0 - p * 768 + c * 8;
      int hq = nn >> 6, hd = nn & 63;
      *(bf16x8*)&dst[(size_t)((bb0 * 12 + hq) * 2048 + s0 + m) * 64 + hd] = v;
    }
  } else {
#pragma unroll
    for (int nt = 0; nt < 4; nt++) {
      int n = nw + nt * 16 + col;
      float bias = bp[n0 + n - 1536];
#pragma unroll
      for (int mt = 0; mt < 4; mt++)
#pragma unroll
        for (int r = 0; r < 4; r++) {
          int m = mw + mt * 16 + quad * 4 + r;
          Cs[n * 136 + m] = (bf16_t)(acc[mt][nt][r] + bias);
        }
    }
    __syncthreads();
#pragma unroll
    for (int i = 0; i < 8; i++) {
      int idx = i * 256 + tid;
      int n = idx >> 4, c = idx & 15;
      bf16x8 v = *(const bf16x8*)&Cs[n * 136 + c * 8];
      int nn = n0 - 1536 + n;
      int hq = nn >> 6, hd = nn & 63;
      *(bf16x8*)&VTo[((size_t)(bb0 * 12 + hq) * 64 + hd) * 2048 + s0 + c * 8] = v;
    }
  }
}

// ---------------------------------------------------------------- K3: attention
// v7 (round-3 best) VERBATIM. Three structural variants all lost:
// ksplit=4 occupancy push (+HBM traffic, 2x slower), register-direct streaming
// (scatter-gather VMEM, 2.4x slower), QK-ahead ping-pong (acc set spilled to
// scratch). Do not restructure.
__global__ __launch_bounds__(256, 3) void attn(const bf16_t* __restrict__ Q,
                                               const bf16_t* __restrict__ K,
                                               const bf16_t* __restrict__ VT,
                                               float* __restrict__ Op,
                                               float* __restrict__ lp) {
  __shared__ __align__(16) char smem[49152];
  bf16_t* Kl = (bf16_t*)smem;            // [3][64*64], XOR-swizzled by row&7
  bf16_t* Vl = (bf16_t*)(smem + 24576);  // [3][64*64], same swizzle
  const int id = blockIdx.x;             // 0..767
  const int rr0 = id >> 3;               // 0..95
  const int bh = (id & 7) * 3 + (rr0 >> 5);  // XCD id&7 owns 3 consecutive bh
  const int w5 = rr0 & 31;
  const int qt = w5 & 15, sp = w5 >> 4;  // q-tile, key-split half
  const int tid = threadIdx.x, wv = tid >> 6, lane = tid & 63;
  const int lq = lane & 31, half = lane >> 5;
  const int q0 = qt * 128 + wv * 32;

  bf16x8 qf[4];  // B-frags of Q^T (per-lane query = lq), register resident
#pragma unroll
  for (int ks = 0; ks < 4; ++ks)
    qf[ks] = *(const bf16x8*)&Q[(size_t)(bh * 2048 + q0 + lq) * 64 + ks * 16 + half * 8];

  f32x16 oacc[2];  // O^T partial: col=q (lane), rows=d
  for (int i = 0; i < 16; i++) { oacc[0][i] = 0.f; oacc[1][i] = 0.f; }
  float l0 = 0.f, l1 = 0.f, l2 = 0.f, l3 = 0.f;  // partial denominators

  const bf16_t* gK = K + (size_t)bh * 2048 * 64 + (size_t)sp * 1024 * 64;
  const bf16_t* gV = VT + (size_t)bh * 64 * 2048 + sp * 1024;
  const int srow = lane >> 3, scc = lane & 7;
  const int cg = scc ^ srow;  // inverse-swizzled source col (row&7 == srow)
  const bf16_t* gKb = gK + srow * 64 + cg * 8;    // + kb*4096 + ii*512
  const bf16_t* gVb = gV + srow * 2048 + cg * 8;  // + ii*16384 + kb*64
  const int kpart = (wv & 1) * 4;  // waves 0,1 stage K chunks 0-3/4-7; 2,3 V

  auto stage = [&](int kb, int buf) {
    if (wv < 2) {
#pragma unroll
      for (int i = 0; i < 4; i++) {
        int ii = kpart + i;
        gload_lds16(gKb + kb * 4096 + ii * 512, Kl + buf * 4096 + ii * 512);
      }
    } else {
#pragma unroll
      for (int i = 0; i < 4; i++) {
        int ii = kpart + i;
        gload_lds16(gVb + (size_t)ii * 16384 + kb * 64, Vl + buf * 4096 + ii * 512);
      }
    }
  };

  stage(0, 0);
  stage(1, 1);
  asm volatile("s_waitcnt vmcnt(4)" ::: "memory");  // buf0 (+Q) done; buf1 flying
  __builtin_amdgcn_s_barrier();
  asm volatile("" ::: "memory");

  int bb = 0, rb = 2;
  for (int kb = 0; kb < 16; ++kb) {
    if (kb < 14) stage(kb + 2, rb);  // 2-deep prefetch, in flight across barriers

    // S^T[key][q] = K_blk @ Q^T   (K pre-scaled by log2e/8 at projection)
    f32x16 sacc[2];
    for (int i = 0; i < 16; i++) { sacc[0][i] = 0.f; sacc[1][i] = 0.f; }
    __builtin_amdgcn_s_setprio(1);
#pragma unroll
    for (int t = 0; t < 2; t++) {
      const int row = t * 32 + lq;
#pragma unroll
      for (int ks = 0; ks < 4; ++ks) {
        bf16x8 kf = *(const bf16x8*)&Kl[bb * 4096 + row * 64 + (((2 * ks + half) ^ (row & 7)) * 8)];
        sacc[t] = __builtin_amdgcn_mfma_f32_32x32x16_bf16(kf, qf[ks], sacc[t], 0, 0, 0);
      }
    }
    __builtin_amdgcn_s_setprio(0);

    // P = exp2(S) (fixed max), l in 4 partial chains
#pragma unroll
    for (int t = 0; t < 2; t++)
#pragma unroll
      for (int rr = 0; rr < 16; rr++) sacc[t][rr] = fexp2(sacc[t][rr]);
#pragma unroll
    for (int rr = 0; rr < 16; rr += 4) {
      l0 += sacc[0][rr + 0] + sacc[1][rr + 0];
      l1 += sacc[0][rr + 1] + sacc[1][rr + 1];
      l2 += sacc[0][rr + 2] + sacc[1][rr + 2];
      l3 += sacc[0][rr + 3] + sacc[1][rr + 3];
    }

    // pack quads: pkq[t][g] = keys t*32 + 8g + 4*half + {0..3}, as 2x u32
    uint32_t pkq[2][4][2];
#pragma unroll
    for (int t = 0; t < 2; t++)
#pragma unroll
      for (int g = 0; g < 4; g++) {
        pkq[t][g][0] = pk_bf16(sacc[t][4 * g + 0], sacc[t][4 * g + 1]);
        pkq[t][g][1] = pk_bf16(sacc[t][4 * g + 2], sacc[t][4 * g + 3]);
      }

    // cross-half exchange -> B-operand frags via permlane32_swap
    bf16x8 pfrag[4];
#pragma unroll
    for (int t = 0; t < 2; t++)
#pragma unroll
      for (int e = 0; e < 2; e++) {
        union { uint32_t u[4]; bf16x8 v; } F;
#pragma unroll
        for (int wd = 0; wd < 2; wd++) {
#if __has_builtin(__builtin_amdgcn_permlane32_swap)
          u32x2 sw = __builtin_amdgcn_permlane32_swap(pkq[t][2 * e][wd],
                                                      pkq[t][2 * e + 1][wd],
                                                      false, false);
          F.u[wd] = sw.x;
          F.u[2 + wd] = sw.y;
#else
          uint32_t s = half ? pkq[t][2 * e][wd] : pkq[t][2 * e + 1][wd];
          uint32_t rx = __shfl_xor(s, 32);
          uint32_t ow = half ? pkq[t][2 * e + 1][wd] : pkq[t][2 * e][wd];
          F.u[wd] = half ? rx : ow;
          F.u[2 + wd] = half ? ow : rx;
#endif
        }
        pfrag[2 * t + e] = F.v;
      }

    // O^T += V^T @ P^T  (A = V frags from LDS, B = pfrag)
    __builtin_amdgcn_s_setprio(1);
#pragma unroll
    for (int c = 0; c < 4; c++) {
#pragma unroll
      for (int dt = 0; dt < 2; dt++) {
        const int vr = dt * 32 + lq;
        bf16x8 vf = *(const bf16x8*)&Vl[bb * 4096 + vr * 64 + (((2 * c + half) ^ (vr & 7)) * 8)];
        oacc[dt] = __builtin_amdgcn_mfma_f32_32x32x16_bf16(vf, pfrag[c], oacc[dt], 0, 0, 0);
      }
    }
    __builtin_amdgcn_s_setprio(0);

    // counted wait: keep newest stage batch (4 loads/wave) in flight
    if (kb < 14) {
      asm volatile("s_waitcnt vmcnt(4)" ::: "memory");
    } else if (kb == 14) {
      asm volatile("s_waitcnt vmcnt(0)" ::: "memory");
    }
    if (kb < 15) {
      __builtin_amdgcn_s_barrier();
      asm volatile("" ::: "memory");
    }
    bb = (bb == 2) ? 0 : bb + 1;
    rb = (rb == 2) ? 0 : rb + 1;
  }

  // epilogue: partial l + unnormalized partial O^T -> Op[q][d] rows
  float l_own = (l0 + l1) + (l2 + l3);
  float l_tot = l_own + __shfl_xor(l_own, 32);
  __syncthreads();  // all K/V reads done; smem becomes 4x 8KB f32 scratch
  float* Of = (float*)smem + wv * 2048;
#pragma unroll
  for (int dt = 0; dt < 2; dt++)
#pragma unroll
    for (int rr = 0; rr < 16; rr++) {
      int d = dt * 32 + (rr & 3) + 8 * (rr >> 2) + 4 * half;
      int g = d >> 2, wd = d & 3;
      Of[lq * 64 + ((g ^ (lq & 15)) * 4) + wd] = oacc[dt][rr];
    }
  if (half == 0) lp[((size_t)sp * 24 + bh) * 2048 + q0 + lq] = l_tot;
  float* ob = Op + (((size_t)sp * 24 + bh) * 2048 + q0) * 64;
#pragma unroll
  for (int i = 0; i < 8; i++) {
    int idx = i * 64 + lane;
    int qq = idx >> 4, c = idx & 15;
    f32x4 v = *(f32x4*)&Of[qq * 64 + ((c ^ (qq & 15)) * 4)];
    *(f32x4*)&ob[(size_t)qq * 64 + c * 4] = v;
  }
}

// ------------------------------------------------- K4: combine split-K partials
// out[b][q][h*64+d] = (Op0 + Op1) / (l0 + l1), with head-merge transpose.
__global__ __launch_bounds__(256) void combine(const float* __restrict__ Op,
                                               const float* __restrict__ lp,
                                               float* __restrict__ out) {
  int g = blockIdx.x * 256 + threadIdx.x;  // over 24*2048*16 = 786432
  int bh = g >> 15;
  int rem = g & 32767;
  int q = rem >> 4, c = rem & 15;
  const size_t plane = (size_t)24 * 2048 * 64;
  size_t o0 = ((size_t)bh * 2048 + q) * 64 + c * 4;
  f32x4 a = *(const f32x4*)&Op[o0];
  f32x4 b2 = *(const f32x4*)&Op[plane + o0];
  float l = lp[bh * 2048 + q] + lp[24 * 2048 + bh * 2048 + q];
  float inv = 1.0f / l;
  int b = bh / 12, head = bh % 12;
  f32x4 r;
#pragma unroll
  for (int j = 0; j < 4; j++) r[j] = (a[j] + b2[j]) * inv;
  *(f32x4*)&out[((size_t)b * 2048 + q) * 768 + head * 64 + c * 4] = r;
}

// -------------------------------------------------------------------- launcher
extern "C" void kernel_launch(void* const* d_in, const int* in_sizes, int n_in,
                              void* d_out, int out_size, void* d_ws, size_t ws_size,
                              hipStream_t stream) {
  const float* hs = (const float*)d_in[0];
  const float* Wq = (const float*)d_in[1];
  const float* bq = (const float*)d_in[2];
  const float* Wk = (const float*)d_in[3];
  const float* bk = (const float*)d_in[4];
  const float* Wv = (const float*)d_in[5];
  const float* bv = (const float*)d_in[6];
  float* out = (float*)d_out;

  char* w = (char*)d_ws;
  bf16_t* hsb = (bf16_t*)w; w += (size_t)4096 * 768 * 2;
  bf16_t* wtb = (bf16_t*)w; w += (size_t)2304 * 768 * 2;
  bf16_t* Qb  = (bf16_t*)w; w += (size_t)24 * 2048 * 64 * 2;
  bf16_t* Kb  = (bf16_t*)w; w += (size_t)24 * 2048 * 64 * 2;
  bf16_t* VTb = (bf16_t*)w; w += (size_t)24 * 2048 * 64 * 2;
  float* Opw  = (float*)w;  w += (size_t)2 * 24 * 2048 * 64 * 4;  // 25.2 MB
  float* lpw  = (float*)w;                                        // 0.39 MB

  hipLaunchKernelGGL(cvt_hs, dim3(3072), dim3(256), 0, stream, hs, hsb);
  hipLaunchKernelGGL(cvt_w, dim3(72, 24), dim3(256), 0, stream, Wq, Wk, Wv, wtb);
  hipLaunchKernelGGL(gemm_qkv, dim3(18, 32), dim3(256), 0, stream, hsb, wtb, bq,
                     bk, bv, Qb, Kb, VTb);
  hipLaunchKernelGGL(attn, dim3(768), dim3(256), 0, stream, Qb, Kb, VTb, Opw, lpw);
  hipLaunchKernelGGL(combine, dim3(3072), dim3(256), 0, stream, Opw, lpw, out);
}